// Round 7
// baseline (3501.955 us; speedup 1.0000x reference)
//
#include <hip/hip_runtime.h>
#include <cstdint>
#include <cstddef>

typedef __bf16 bf16x8 __attribute__((ext_vector_type(8)));
typedef float f32x4 __attribute__((ext_vector_type(4)));

#define HD 256
#define TLEN 1000
#define NSTEP 999
#define BTILE 4

// ws layout (bf16 elements): W1X | W1Z | W1C | W2R | W3R | W4R, fragment-ordered
#define W1X_OFF 0
#define W1Z_OFF 8192
#define W1C_OFF 16384
#define W2R_OFF 24576
#define W3R_OFF 90112
#define W4R_OFF 155648
#define WS_ELEMS 159744

__device__ __forceinline__ void wg_barrier() {
  // LDS-only drain + barrier: do NOT force vmcnt(0) like __syncthreads does,
  // so the z-prefetch / out-stores stay in flight across layer barriers.
  asm volatile("s_waitcnt lgkmcnt(0)\n\ts_barrier" ::: "memory");
}

// Repack fp32 weights -> bf16 MFMA A-fragments.
// Layer-1 telescoped:  h1_pre = u + z_eff*W1z + c1,  u := x*W1x maintained as
// an MFMA accumulator (u += dt*(dx+b4)*W1x each step).
//   W1x = W1[16:24]+W1[32:40]   (A rows k=0..7)
//   W1z = W1[24:32]+W1[40:48]   (A rows k=8..15)
//   W1c: k0-7 = W1[0:8]-W1[16:24], k8-15 = W1[8:16]-W1[24:32], k16 = b1
// W2/W3/W4 fragment layout unchanged from the verified r4 kernel:
//   k = kb*32 + (lane>>4)*8 + j ; n = w*32 + tt*16 + (lane&15)
__global__ void prep_weights(const float* __restrict__ W1, const float* __restrict__ b1,
                             const float* __restrict__ W2, const float* __restrict__ W3,
                             const float* __restrict__ W4, __bf16* __restrict__ ws) {
  int tid = blockIdx.x * blockDim.x + threadIdx.x;
  if (tid >= WS_ELEMS) return;
  float val = 0.0f;
  if (tid < W1Z_OFF) {                       // W1X: 8w x 2tt x 64lane x 8j
    int t = tid;
    int j = t & 7, lane = (t >> 3) & 63, tt = (t >> 9) & 1, w = (t >> 10) & 7;
    int k = ((lane >> 4) * 8) + j;
    int n = w * 32 + tt * 16 + (lane & 15);
    if (k < 8) val = W1[(16 + k) * HD + n] + W1[(32 + k) * HD + n];
  } else if (tid < W1C_OFF) {                // W1Z
    int t = tid - W1Z_OFF;
    int j = t & 7, lane = (t >> 3) & 63, tt = (t >> 9) & 1, w = (t >> 10) & 7;
    int k = ((lane >> 4) * 8) + j;
    int n = w * 32 + tt * 16 + (lane & 15);
    if (k >= 8 && k < 16) { int d = k - 8; val = W1[(24 + d) * HD + n] + W1[(40 + d) * HD + n]; }
  } else if (tid < W2R_OFF) {                // W1C
    int t = tid - W1C_OFF;
    int j = t & 7, lane = (t >> 3) & 63, tt = (t >> 9) & 1, w = (t >> 10) & 7;
    int k = ((lane >> 4) * 8) + j;
    int n = w * 32 + tt * 16 + (lane & 15);
    if (k < 8) val = W1[k * HD + n] - W1[(16 + k) * HD + n];
    else if (k < 16) { int d = k - 8; val = W1[(8 + d) * HD + n] - W1[(24 + d) * HD + n]; }
    else if (k == 16) val = b1[n];
  } else if (tid < W3R_OFF) {                // W2R: 8w x 8kb x 2tt x 64 x 8
    int t = tid - W2R_OFF;
    int j = t & 7, lane = (t >> 3) & 63, tt = (t >> 9) & 1, kb = (t >> 10) & 7, w = (t >> 13) & 7;
    int k = kb * 32 + ((lane >> 4) * 8) + j;
    int n = w * 32 + tt * 16 + (lane & 15);
    val = W2[k * HD + n];
  } else if (tid < W4R_OFF) {                // W3R
    int t = tid - W3R_OFF;
    int j = t & 7, lane = (t >> 3) & 63, tt = (t >> 9) & 1, kb = (t >> 10) & 7, w = (t >> 13) & 7;
    int k = kb * 32 + ((lane >> 4) * 8) + j;
    int n = w * 32 + tt * 16 + (lane & 15);
    val = W3[k * HD + n];
  } else {                                   // W4R: 8kb x 64 x 8, N padded 8->16 with zeros
    int t = tid - W4R_OFF;
    int j = t & 7, lane = (t >> 3) & 63, kb = (t >> 9) & 7;
    int k = kb * 32 + ((lane >> 4) * 8) + j;
    int n = lane & 15;
    val = (n < 8) ? W4[k * 8 + n] : 0.0f;
  }
  ws[tid] = (__bf16)val;
}

// r6 post-mortem: r4 (8 waves, masked reads) is the LDS-clean config; its
// remaining tail {L4 partial -> bar -> wave-0 reduce + x/z LDS round trip ->
// bar} is removed here by telescoping x through W1:
//   u := x*W1x kept as per-wave MFMA C-accumulator; step = 3 phases/3 barriers:
//   A: p4 reduce -> g4=dt*(dx+b4) -> x-reg update/out store -> shfl_xor(16)
//      -> u-MFMA + z-MFMA -> h1=ELU(u+Pz+c1) -> hA
//   B: layer2 (r4 code)   C: layer3 + fused W4 partial -> p4
__global__ __launch_bounds__(512, 2) void ode_main(
    const float* __restrict__ t_g, const float* __restrict__ x_g,
    const float* __restrict__ z_g, const float* __restrict__ ev_g,
    const float* __restrict__ zj_g, const float* __restrict__ b2_g,
    const float* __restrict__ b3_g, const float* __restrict__ b4_g,
    const __bf16* __restrict__ ws, float* __restrict__ out) {
  __shared__ __align__(16) __bf16 h_a[16 * 264];   // 16 rows kept (4 live), row 528B
  __shared__ __align__(16) __bf16 h_b[16 * 264];
  __shared__ __align__(16) __bf16 h_c[16 * 264];
  __shared__ __align__(16) float p4[8 * 32];       // [wave][bcol*8 + dim]
  __shared__ __align__(16) float x0s[16 * 8];      // init staging only
  __shared__ __align__(16) float z0s[16 * 8];

  const int tid  = threadIdx.x;
  const int lane = tid & 63;
  const int wid  = tid >> 6;     // 8 waves; wave w owns hidden cols [32w, 32w+32)
  const int bcol = lane & 15;    // B/C-operand column; batch row if < BTILE
  const int q    = lane >> 4;    // quad
  const int b0   = blockIdx.x * BTILE;
  const bool live = bcol < BTILE;
  const size_t gb = (size_t)(b0 + (live ? bcol : 0));   // safe base; masked use

  // ---- stage x0/z0 (rows >= BTILE zeroed) + zero p4 ----
  if (tid < 128) {
    int m = tid >> 3, d = tid & 7;
    if (m < BTILE) {
      size_t g = (size_t)(b0 + m);
      x0s[m * 8 + d] = x_g[g * (TLEN * 8) + d];
      z0s[m * 8 + d] = z_g[g * (TLEN * 8) + d];
    } else {
      x0s[m * 8 + d] = 0.f;
      z0s[m * 8 + d] = 0.f;
    }
  }
  if (tid < 256) p4[tid] = 0.f;
  __syncthreads();

  // ---- resident weight fragments ----
  const bf16x8* wsv = (const bf16x8*)ws;
  bf16x8 w1xf[2], w1zf[2], w2f[8][2], w3f[8][2];
#pragma unroll
  for (int tt = 0; tt < 2; ++tt) {
    w1xf[tt] = wsv[(W1X_OFF / 8) + (wid * 2 + tt) * 64 + lane];
    w1zf[tt] = wsv[(W1Z_OFF / 8) + (wid * 2 + tt) * 64 + lane];
  }
#pragma unroll
  for (int kb = 0; kb < 8; ++kb)
#pragma unroll
    for (int tt = 0; tt < 2; ++tt) {
      w2f[kb][tt] = wsv[(W2R_OFF / 8) + ((wid * 8 + kb) * 2 + tt) * 64 + lane];
      w3f[kb][tt] = wsv[(W3R_OFF / 8) + ((wid * 8 + kb) * 2 + tt) * 64 + lane];
    }
  bf16x8 w4f = wsv[(W4R_OFF / 8) + wid * 64 + lane];  // W4 k-slice for this wave

  // biases as C-init: lane's 4 C rows are hidden n = wid*32 + tt*16 + q*4 + e
  f32x4 b2v[2], b3v[2];
#pragma unroll
  for (int tt = 0; tt < 2; ++tt) {
    int n0 = wid * 32 + tt * 16 + q * 4;
    b2v[tt] = *(const f32x4*)(b2_g + n0);
    b3v[tt] = *(const f32x4*)(b3_g + n0);
  }
  f32x4 b4v = {0.f, 0.f, 0.f, 0.f};
  if (q < 2) b4v = *(const f32x4*)(b4_g + q * 4);

  bf16x8 zf;
#pragma unroll
  for (int e = 0; e < 8; ++e) zf[e] = (__bf16)0.f;

  // q1 personals: event + z_jump + z prefetch (8 dims of batch bcol)
  float ev1 = 0.f;
  f32x4 zjA = {0.f, 0.f, 0.f, 0.f}, zjB = {0.f, 0.f, 0.f, 0.f};
  f32x4 zpA = {0.f, 0.f, 0.f, 0.f}, zpB = {0.f, 0.f, 0.f, 0.f};
  if (q == 1 && live) {
    ev1 = ev_g[gb];
    zjA = *(const f32x4*)(zj_g + gb * 8);
    zjB = *(const f32x4*)(zj_g + gb * 8 + 4);
    zpA = *(const f32x4*)(z_g + gb * (TLEN * 8));      // z(:,0)
    zpB = *(const f32x4*)(z_g + gb * (TLEN * 8) + 4);
  }

  // per-lane x state (q<2): dims q*4..q*4+3 of batch bcol (dead rows read 0s)
  f32x4 x4 = {0.f, 0.f, 0.f, 0.f};
  if (q < 2) x4 = *(const f32x4*)(x0s + bcol * 8 + q * 4);

  // ---- u0 = x0*W1x ; c1 = x0*(W1a-W1c) + z0*(W1b-W1d) + b1 (one-shot MFMAs) ----
  f32x4 u[2], c1[2];
  {
    bf16x8 x0frag = zf, cfrag = zf;
    if (q == 0) {
      const float* xp = x0s + bcol * 8;
#pragma unroll
      for (int e = 0; e < 8; ++e) { x0frag[e] = (__bf16)xp[e]; cfrag[e] = (__bf16)xp[e]; }
    } else if (q == 1) {
      const float* zp = z0s + bcol * 8;
#pragma unroll
      for (int e = 0; e < 8; ++e) cfrag[e] = (__bf16)zp[e];
    } else if (q == 2) {
      cfrag[0] = (__bf16)1.0f;                 // k=16 -> b1 row
    }
    f32x4 z4 = {0.f, 0.f, 0.f, 0.f};
#pragma unroll
    for (int tt = 0; tt < 2; ++tt) {
      bf16x8 w1cf = wsv[(W1C_OFF / 8) + (wid * 2 + tt) * 64 + lane];
      u[tt]  = __builtin_amdgcn_mfma_f32_16x16x32_bf16(w1xf[tt], x0frag, z4, 0, 0, 0);
      c1[tt] = __builtin_amdgcn_mfma_f32_16x16x32_bf16(w1cf, cfrag, z4, 0, 0, 0);
    }
  }

  float tc = t_g[0];
  float tn_hold = tc;

  // persistent masked-read destinations: dead lanes keep zeros forever.
  bf16x8 bfr[8];
#pragma unroll
  for (int kb = 0; kb < 8; ++kb) bfr[kb] = zf;
  bf16x8 h4r = zf;

  auto layer = [&](const __bf16* src, __bf16* dst, const bf16x8 (*wf)[2], const f32x4* bv) {
    const bf16x8* hp = (const bf16x8*)src;
    if (live) {   // masked reads: dead lanes generate no LDS traffic
#pragma unroll
      for (int kb = 0; kb < 8; ++kb) bfr[kb] = hp[bcol * 33 + kb * 4 + q];  // ds_read_b128 x8
    }
#pragma unroll
    for (int tt = 0; tt < 2; ++tt) {
      f32x4 c = bv[tt];
#pragma unroll
      for (int kb = 0; kb < 8; ++kb)
        c = __builtin_amdgcn_mfma_f32_16x16x32_bf16(wf[kb][tt], bfr[kb], c, 0, 0, 0);
      union { __bf16 h4[4]; unsigned long long u; } pk;
#pragma unroll
      for (int e = 0; e < 4; ++e) {
        float v = c[e];
        v = (v > 0.f) ? v : (__expf(v) - 1.0f);  // ELU
        pk.h4[e] = (__bf16)v;
      }
      if (live)
        *(unsigned long long*)(dst + bcol * 264 + wid * 32 + tt * 16 + q * 4) = pk.u;
    }
  };

  __syncthreads();

#pragma unroll 1
  for (int i = 0; i <= NSTEP; ++i) {
    // ---- phase A: finish step i-1 (p4 reduce -> u,x) + start step i (h1) ----
    float tn = tn_hold;
    float dt = tn - tc;
    tc = tn;
    f32x4 g4 = {0.f, 0.f, 0.f, 0.f};
    if (q < 2 && live) {
      const float* pp = p4 + bcol * 8 + q * 4;
      f32x4 a0 = *(const f32x4*)(pp + 0 * 32);
      f32x4 a1 = *(const f32x4*)(pp + 1 * 32);
      f32x4 a2 = *(const f32x4*)(pp + 2 * 32);
      f32x4 a3 = *(const f32x4*)(pp + 3 * 32);
      f32x4 a4 = *(const f32x4*)(pp + 4 * 32);
      f32x4 a5 = *(const f32x4*)(pp + 5 * 32);
      f32x4 a6 = *(const f32x4*)(pp + 6 * 32);
      f32x4 a7 = *(const f32x4*)(pp + 7 * 32);
      f32x4 s = ((a0 + a1) + (a2 + a3)) + ((a4 + a5) + (a6 + a7));
#pragma unroll
      for (int e = 0; e < 4; ++e) g4[e] = dt * (s[e] + b4v[e]);
      x4 += g4;                                 // x_i = x_{i-1} + dt*(dx+b4)
      if (wid == 0)                             // out[:, i]; fire-and-forget
        *(f32x4*)(out + gb * (TLEN * 8) + (size_t)i * 8 + q * 4) = x4;
    }
    if (i == NSTEP) break;                      // uniform: last x stored, done

    // gather dims 4-7 (q1 -> q0) for the u-update B-frag
    f32x4 o4;
#pragma unroll
    for (int e = 0; e < 4; ++e) o4[e] = __shfl_xor(g4[e], 16);
    bf16x8 dxfrag = zf;
    if (q == 0 && live) {
#pragma unroll
      for (int e = 0; e < 4; ++e) { dxfrag[e] = (__bf16)g4[e]; dxfrag[e + 4] = (__bf16)o4[e]; }
    }
    u[0] = __builtin_amdgcn_mfma_f32_16x16x32_bf16(w1xf[0], dxfrag, u[0], 0, 0, 0);
    u[1] = __builtin_amdgcn_mfma_f32_16x16x32_bf16(w1xf[1], dxfrag, u[1], 0, 0, 0);

    // z_eff(i) on q1 lanes (prefetched z + event select), k=8..15 of the frag
    bf16x8 zfrag = zf;
    if (q == 1 && live) {
      bool jmp = (tn >= ev1);
#pragma unroll
      for (int e = 0; e < 4; ++e) {
        float za = jmp ? zjA[e] : zpA[e];
        float zb = jmp ? zjB[e] : zpB[e];
        zfrag[e] = (__bf16)za;
        zfrag[e + 4] = (__bf16)zb;
      }
    }
    f32x4 z4i = {0.f, 0.f, 0.f, 0.f};
    f32x4 pz0 = __builtin_amdgcn_mfma_f32_16x16x32_bf16(w1zf[0], zfrag, z4i, 0, 0, 0);
    f32x4 pz1 = __builtin_amdgcn_mfma_f32_16x16x32_bf16(w1zf[1], zfrag, z4i, 0, 0, 0);

    // h1 = ELU(u + Pz + c1) -> h_a
#pragma unroll
    for (int tt = 0; tt < 2; ++tt) {
      f32x4 pre = u[tt] + (tt ? pz1 : pz0) + c1[tt];
      union { __bf16 h4[4]; unsigned long long u; } pk;
#pragma unroll
      for (int e = 0; e < 4; ++e) {
        float v = pre[e];
        v = (v > 0.f) ? v : (__expf(v) - 1.0f);
        pk.h4[e] = (__bf16)v;
      }
      if (live)
        *(unsigned long long*)(h_a + bcol * 264 + wid * 32 + tt * 16 + q * 4) = pk.u;
    }
    wg_barrier();

    // ---- phase B: layer 2; prefetch z(i+1) + t(i+1) under it ----
    if (q == 1 && live) {
      zpA = *(const f32x4*)(z_g + gb * (TLEN * 8) + (size_t)(i + 1) * 8);
      zpB = *(const f32x4*)(z_g + gb * (TLEN * 8) + (size_t)(i + 1) * 8 + 4);
    }
    tn_hold = t_g[i + 1];
    layer(h_a, h_b, w2f, b2v);
    wg_barrier();

    // ---- phase C: layer 3 + fused W4 partial on OWN 32 cols -> p4 ----
    layer(h_b, h_c, w3f, b3v);
    {
      const bf16x8* hp = (const bf16x8*)h_c;
      if (live) h4r = hp[bcol * 33 + wid * 4 + q];   // same-wave RAW (r4-proven)
      f32x4 c = {0.f, 0.f, 0.f, 0.f};
      c = __builtin_amdgcn_mfma_f32_16x16x32_bf16(w4f, h4r, c, 0, 0, 0);
      if (q < 2 && live)
        *(f32x4*)(p4 + wid * 32 + bcol * 8 + q * 4) = c;
    }
    wg_barrier();
  }
}

extern "C" void kernel_launch(void* const* d_in, const int* in_sizes, int n_in,
                              void* d_out, int out_size, void* d_ws, size_t ws_size,
                              hipStream_t stream) {
  const float* t  = (const float*)d_in[0];
  const float* x  = (const float*)d_in[1];
  const float* z  = (const float*)d_in[2];
  const float* ev = (const float*)d_in[3];
  const float* zj = (const float*)d_in[4];
  const float* W1 = (const float*)d_in[5];
  const float* b1 = (const float*)d_in[6];
  const float* W2 = (const float*)d_in[7];
  const float* b2 = (const float*)d_in[8];
  const float* W3 = (const float*)d_in[9];
  const float* b3 = (const float*)d_in[10];
  const float* W4 = (const float*)d_in[11];
  const float* b4 = (const float*)d_in[12];
  __bf16* ws = (__bf16*)d_ws;
  float* out = (float*)d_out;

  prep_weights<<<624, 256, 0, stream>>>(W1, b1, W2, W3, W4, ws);
  ode_main<<<256, 512, 0, stream>>>(t, x, z, ev, zj, b2, b3, b4, ws, out);
}